// Round 4
// baseline (74.547 us; speedup 1.0000x reference)
//
#include <hip/hip_runtime.h>
#include <hip/hip_bf16.h>

#define B_ 8
#define N_ 1024
#define D_ 256
#define M_ (B_ * N_)   // 8192

typedef __attribute__((ext_vector_type(8))) short bf16x8;
typedef __attribute__((ext_vector_type(8))) unsigned short u16x8;
typedef __attribute__((ext_vector_type(4))) float f32x4;

// per-batch barrier state: module globals (NOT in d_ws — workspace is poisoned
// between iterations). Sense-reversing: survives graph replay.
__device__ unsigned bar_cnt[8];
__device__ unsigned bar_sense[8];

__device__ __forceinline__ unsigned short f2bf(float f) {
    unsigned int u = __float_as_uint(f);
    u += 0x7fffu + ((u >> 16) & 1u);   // RNE to bf16
    return (unsigned short)(u >> 16);
}
// HW packed convert: 2 f32 -> 2 bf16 (RNE), 1 instruction
__device__ __forceinline__ unsigned int cvtpk(float lo, float hi) {
    unsigned int r;
    asm("v_cvt_pk_bf16_f32 %0, %1, %2" : "=v"(r) : "v"(lo), "v"(hi));
    return r;
}
__device__ __forceinline__ bf16x8 load8_f32_bf(const float* __restrict__ p) {
    const float4* q = (const float4*)p;
    float4 u = q[0], v = q[1];
    union { unsigned int u4[4]; bf16x8 v8; } c;
    c.u4[0] = cvtpk(u.x, u.y); c.u4[1] = cvtpk(u.z, u.w);
    c.u4[2] = cvtpk(v.x, v.y); c.u4[3] = cvtpk(v.z, v.w);
    return c.v8;
}

// ===== fused single kernel: phase A (h-GEMM + s1/s2 + adj->mask) =====
//       -> per-batch device barrier (32 blocks) ->
//       phase B (exp scores -> LDS -> attention GEMM -> elu)
// Block (bid): b = bid&7, i0 = (bid>>3)*32. Phase-A rows m0 = b*N + i0 equal
// phase-B rows, so s1/mask for own rows are self-produced; s2/hT of the whole
// batch come from the 31 sibling blocks via the barrier.
__global__ __launch_bounds__(512) void k_all(
        const float* __restrict__ x, const float* __restrict__ W,
        const float* __restrict__ a1, const float* __restrict__ a2,
        const int* __restrict__ adj,
        unsigned short* __restrict__ hT,
        float* __restrict__ s1, float* __restrict__ s2,
        unsigned long long* __restrict__ mask,
        float* __restrict__ out) {
    __shared__ unsigned short xs[32 * 256];        // 16 KB, XOR-swizzled rows
    __shared__ unsigned short tls[8][32][40];      // 20 KB h tile
    __shared__ float spart[8][32][9];              // 9 KB s partials
    __shared__ unsigned short Pe[32 * 1024];       // 64 KB exp-score tile
    __shared__ float invl[32];                     // total 109 KB -> 1 block/CU

    const int tid = threadIdx.x;
    const int bid = blockIdx.x;
    const int b  = bid & 7;
    const int i0 = (bid >> 3) << 5;
    const int m0 = b * N_ + i0;                    // == old mt*32 mapping

    // ========================= phase A =========================
    {
        const int wslot = tid >> 6, lane = tid & 63;
        const int n0 = wslot * 32;
        char* xc = (char*)xs;

        // stage x tile: 32 rows x 256 cols f32 -> bf16, swizzled
        {
            const int row = tid >> 4, colg = (tid & 15) * 16;
            const float4* xp = (const float4*)(x + (m0 + row) * D_ + colg);
            float4 f0 = xp[0], f1 = xp[1], f2 = xp[2], f3 = xp[3];
            union { unsigned int u4[8]; u16x8 v8[2]; } c;
            c.u4[0] = cvtpk(f0.x, f0.y); c.u4[1] = cvtpk(f0.z, f0.w);
            c.u4[2] = cvtpk(f1.x, f1.y); c.u4[3] = cvtpk(f1.z, f1.w);
            c.u4[4] = cvtpk(f2.x, f2.y); c.u4[5] = cvtpk(f2.z, f2.w);
            c.u4[6] = cvtpk(f3.x, f3.y); c.u4[7] = cvtpk(f3.z, f3.w);
            const int base = row * 512 + colg * 2, sw = (row & 7) << 4;
            *(u16x8*)(xc + ((base) ^ sw))      = c.v8[0];
            *(u16x8*)(xc + ((base + 16) ^ sw)) = c.v8[1];
        }
        __syncthreads();

        const int r = lane & 15, kg = lane >> 4;
        const int sw = (r & 7) << 4;
        const int abase0 = r * 512, abase1 = (16 + r) * 512;
        const float* wb0 = W + (n0 + r) * D_ + kg * 8;
        const float* wb1 = wb0 + 16 * D_;
        f32x4 z = {0.f, 0.f, 0.f, 0.f};
        f32x4 acc00 = z, acc01 = z, acc10 = z, acc11 = z;
        bf16x8 nb0 = load8_f32_bf(wb0);
        bf16x8 nb1 = load8_f32_bf(wb1);
        #pragma unroll
        for (int d0 = 0; d0 < D_; d0 += 32) {
            const int kb = (d0 + kg * 8) * 2;
            bf16x8 a0 = *(const bf16x8*)(xc + ((abase0 + kb) ^ sw));
            bf16x8 a1f = *(const bf16x8*)(xc + ((abase1 + kb) ^ sw));
            bf16x8 b0 = nb0, b1 = nb1;
            if (d0 + 32 < D_) {
                nb0 = load8_f32_bf(wb0 + d0 + 32);
                nb1 = load8_f32_bf(wb1 + d0 + 32);
            }
            acc00 = __builtin_amdgcn_mfma_f32_16x16x32_bf16(a0, b0, acc00, 0, 0, 0);
            acc01 = __builtin_amdgcn_mfma_f32_16x16x32_bf16(a0, b1, acc01, 0, 0, 0);
            acc10 = __builtin_amdgcn_mfma_f32_16x16x32_bf16(a1f, b0, acc10, 0, 0, 0);
            acc11 = __builtin_amdgcn_mfma_f32_16x16x32_bf16(a1f, b1, acc11, 0, 0, 0);
        }
        const int col = lane & 15, rb = (lane >> 4) * 4;
        f32x4 accs[2][2] = {{acc00, acc01}, {acc10, acc11}};
        #pragma unroll
        for (int rt = 0; rt < 2; ++rt)
          #pragma unroll
          for (int ct = 0; ct < 2; ++ct)
            #pragma unroll
            for (int q = 0; q < 4; ++q)
                tls[wslot][rt * 16 + rb + q][ct * 16 + col] = f2bf(accs[rt][ct][q]);
        __syncthreads();

        // s1/s2 partials via MFMA
        {
            bf16x8 bfr = {0, 0, 0, 0, 0, 0, 0, 0};
            if (r < 8) {
                const float* ap = (r < 4 ? a1 + r * D_ : a2 + (r - 4) * D_) + n0 + kg * 8;
                bfr = load8_f32_bf(ap);
            }
            bf16x8 af0 = *(const bf16x8*)&tls[wslot][r][kg * 8];
            bf16x8 af1 = *(const bf16x8*)&tls[wslot][16 + r][kg * 8];
            f32x4 s0 = __builtin_amdgcn_mfma_f32_16x16x32_bf16(af0, bfr, z, 0, 0, 0);
            f32x4 s1v = __builtin_amdgcn_mfma_f32_16x16x32_bf16(af1, bfr, z, 0, 0, 0);
            if (col < 8) {
                #pragma unroll
                for (int q = 0; q < 4; ++q) {
                    spart[wslot][rb + q][col] = s0[q];
                    spart[wslot][16 + rb + q][col] = s1v[q];
                }
            }
        }

        // transposed, coalesced hT write: hT[b][o][n]
        {
            const int bb = m0 >> 10, nbase = m0 & 1023;
            const int ol = lane >> 1, nh = lane & 1;
            unsigned short vv[16];
            #pragma unroll
            for (int q2 = 0; q2 < 16; ++q2) vv[q2] = tls[wslot][nh * 16 + q2][ol];
            u16x8 lo, hi;
            #pragma unroll
            for (int q2 = 0; q2 < 8; ++q2) { lo[q2] = vv[q2]; hi[q2] = vv[8 + q2]; }
            unsigned short* dst = hT + ((size_t)(bb * D_ + n0 + ol)) * N_ + nbase + nh * 16;
            *(u16x8*)dst = lo;
            *(u16x8*)(dst + 8) = hi;
        }

        __syncthreads();
        // reduce s partials across 8 waves, write s1/s2
        if (tid < 256) {
            const int row = tid >> 3, s = tid & 7;
            float v = 0.f;
            #pragma unroll
            for (int wv = 0; wv < 8; ++wv) v += spart[wv][row][s];
            if (s < 4) s1[s * M_ + m0 + row] = v;
            else       s2[(s - 4) * M_ + m0 + row] = v;
        }

        // adj -> 1-bit mask for own 32 rows (ballot compaction)
        {
            const int wrow = m0 + wslot * 4;
            #pragma unroll
            for (int rp = 0; rp < 2; ++rp) {
                int a0v[16], a1v[16];
                const int* r0p = adj + (size_t)(wrow + rp * 2) * N_ + lane;
                const int* r1p = r0p + N_;
                #pragma unroll
                for (int seg = 0; seg < 16; ++seg) {
                    a0v[seg] = __builtin_nontemporal_load(r0p + seg * 64);
                    a1v[seg] = __builtin_nontemporal_load(r1p + seg * 64);
                }
                unsigned long long w0 = 0, w1 = 0;
                #pragma unroll
                for (int seg = 0; seg < 16; ++seg) {
                    unsigned long long b0 = __ballot(a0v[seg] != 0);
                    unsigned long long b1 = __ballot(a1v[seg] != 0);
                    if (lane == seg) { w0 = b0; w1 = b1; }
                }
                if (lane < 16) {
                    mask[(size_t)(wrow + rp * 2) * 16 + lane]     = w0;
                    mask[(size_t)(wrow + rp * 2 + 1) * 16 + lane] = w1;
                }
            }
        }
    }

    // ============ per-batch barrier: 32 producer blocks of batch b ==========
    asm volatile("s_waitcnt vmcnt(0)" ::: "memory");   // drain this thread's stores
    __syncthreads();                                    // whole block drained
    if (tid == 0) {
        __threadfence();                                // device-scope release
        unsigned my = atomicAdd(&bar_sense[b], 0u);     // capture BEFORE arrival
        unsigned old = atomicAdd(&bar_cnt[b], 1u);
        if (old == 31u) {
            atomicExch(&bar_cnt[b], 0u);
            __threadfence();
            atomicAdd(&bar_sense[b], 1u);
        } else {
            while (atomicAdd(&bar_sense[b], 0u) == my) __builtin_amdgcn_s_sleep(2);
        }
        __threadfence();                                // device-scope acquire
    }
    __syncthreads();
    asm volatile("" ::: "memory");                      // no load hoisting above

    // ========================= phase B =========================
    const int w = tid >> 6, lane = tid & 63;
    const int r = lane & 15, kg = lane >> 4;
    const int o0 = w << 5;
    const unsigned short* hTb = hT + (((size_t)b) << 18);
    const unsigned short* pb0 = hTb + (o0 + r) * N_ + kg * 8;
    const unsigned short* pb1 = pb0 + 16 * N_;
    bf16x8 c00 = *(const bf16x8*)pb0;
    bf16x8 c10 = *(const bf16x8*)pb1;
    bf16x8 c01 = *(const bf16x8*)(pb0 + 32);
    bf16x8 c11 = *(const bf16x8*)(pb1 + 32);

    // phase B.1: e = mask_bit * exp(att); thread tj owns j in [tj*64, +64)
    {
        const int ir = tid >> 4, tj = tid & 15;
        const int i = i0 + ir;
        const int gr = b * N_ + i;
        const float s1i0 = s1[0 * M_ + gr], s1i1 = s1[1 * M_ + gr];
        const float s1i2 = s1[2 * M_ + gr], s1i3 = s1[3 * M_ + gr];
        float base; int ko;
        if (i < 512) {
            if (tj < 8)       { base = 0.f;  ko = -1; }
            else if (tj < 12) { base = s1i2; ko = 2 * M_; }
            else              { base = s1i3; ko = 3 * M_; }
        } else if (i < 768) {
            if (tj < 8)       { base = s1i2; ko = 2 * M_; }
            else if (tj < 12) { base = s1i1; ko = 1 * M_; }
            else              { base = 0.f;  ko = -1; }
        } else {
            if (tj < 8)       { base = s1i3; ko = 3 * M_; }
            else              { base = 0.f;  ko = -1; }
        }
        float dval; { float t = s1i0 + s2[b * N_ + i]; dval = fmaxf(t, 0.2f * t); }
        const unsigned long long m = mask[(size_t)gr * 16 + tj];
        const float* s2k = s2 + b * N_ + (ko < 0 ? 0 : ko) + tj * 64;
        float lsum = 0.f;
        #pragma unroll
        for (int qq = 0; qq < 8; ++qq) {
            const int q8 = (qq + tj) & 7;      // rotated order: conflict-free LDS
            const int j0 = tj * 64 + q8 * 8;
            float sv[8];
            if (ko >= 0) {
                float4 v0 = *(const float4*)(s2k + q8 * 8);
                float4 v1 = *(const float4*)(s2k + q8 * 8 + 4);
                sv[0] = v0.x; sv[1] = v0.y; sv[2] = v0.z; sv[3] = v0.w;
                sv[4] = v1.x; sv[5] = v1.y; sv[6] = v1.z; sv[7] = v1.w;
            } else {
                #pragma unroll
                for (int q = 0; q < 8; ++q) sv[q] = 0.f;
            }
            const unsigned int mb = (unsigned int)(m >> (q8 * 8)) & 0xffu;
            float evv[8];
            #pragma unroll
            for (int q = 0; q < 8; ++q) {
                const int j = j0 + q;
                float t = base + sv[q];
                float att = fmaxf(t, 0.2f * t);     // leaky relu
                if (j == i) att = dval;             // diag (m0) override
                const float ev = ((mb >> q) & 1u) ? __expf(att) : 0.f;
                lsum += ev;
                evv[q] = ev;
            }
            union { unsigned int u4[4]; u16x8 v8; } c8;
            c8.u4[0] = cvtpk(evv[0], evv[1]); c8.u4[1] = cvtpk(evv[2], evv[3]);
            c8.u4[2] = cvtpk(evv[4], evv[5]); c8.u4[3] = cvtpk(evv[6], evv[7]);
            *(u16x8*)((char*)Pe + ((ir * 2048 + j0 * 2) ^ ((ir & 7) << 4))) = c8.v8;
        }
        lsum += __shfl_xor(lsum, 1, 64);
        lsum += __shfl_xor(lsum, 2, 64);
        lsum += __shfl_xor(lsum, 4, 64);
        lsum += __shfl_xor(lsum, 8, 64);
        if (tj == 0) invl[ir] = 1.f / lsum;
    }
    __syncthreads();

    // phase B.2: out = elu((Pe @ h) * invl), depth-2 B prefetch
    f32x4 z = {0.f, 0.f, 0.f, 0.f};
    f32x4 acc00 = z, acc01 = z, acc10 = z, acc11 = z;
    const char* Pc = (const char*)Pe;
    const int sw0 = (r & 7) << 4;
    const int base0 = r * 2048, base1 = (16 + r) * 2048;
    #pragma unroll 2
    for (int k0 = 0; k0 < N_; k0 += 64) {
        int kb = (k0 + kg * 8) * 2;
        bf16x8 a0 = *(const bf16x8*)(Pc + ((base0 + kb) ^ sw0));
        bf16x8 a1f = *(const bf16x8*)(Pc + ((base1 + kb) ^ sw0));
        bf16x8 b0 = c00, b1 = c10;
        if (k0 + 64 < N_) {
            c00 = *(const bf16x8*)(pb0 + k0 + 64);
            c10 = *(const bf16x8*)(pb1 + k0 + 64);
        }
        acc00 = __builtin_amdgcn_mfma_f32_16x16x32_bf16(a0, b0, acc00, 0, 0, 0);
        acc01 = __builtin_amdgcn_mfma_f32_16x16x32_bf16(a0, b1, acc01, 0, 0, 0);
        acc10 = __builtin_amdgcn_mfma_f32_16x16x32_bf16(a1f, b0, acc10, 0, 0, 0);
        acc11 = __builtin_amdgcn_mfma_f32_16x16x32_bf16(a1f, b1, acc11, 0, 0, 0);
        kb = (k0 + 32 + kg * 8) * 2;
        a0 = *(const bf16x8*)(Pc + ((base0 + kb) ^ sw0));
        a1f = *(const bf16x8*)(Pc + ((base1 + kb) ^ sw0));
        b0 = c01; b1 = c11;
        if (k0 + 96 < N_) {
            c01 = *(const bf16x8*)(pb0 + k0 + 96);
            c11 = *(const bf16x8*)(pb1 + k0 + 96);
        }
        acc00 = __builtin_amdgcn_mfma_f32_16x16x32_bf16(a0, b0, acc00, 0, 0, 0);
        acc01 = __builtin_amdgcn_mfma_f32_16x16x32_bf16(a0, b1, acc01, 0, 0, 0);
        acc10 = __builtin_amdgcn_mfma_f32_16x16x32_bf16(a1f, b0, acc10, 0, 0, 0);
        acc11 = __builtin_amdgcn_mfma_f32_16x16x32_bf16(a1f, b1, acc11, 0, 0, 0);
    }
    const int col = lane & 15, rb = (lane >> 4) << 2;
    f32x4 accs[2][2] = {{acc00, acc01}, {acc10, acc11}};
    #pragma unroll
    for (int rt = 0; rt < 2; ++rt) {
        #pragma unroll
        for (int q = 0; q < 4; ++q) {
            const int il = rt * 16 + rb + q;
            const float sc = invl[il];
            #pragma unroll
            for (int ct = 0; ct < 2; ++ct) {
                float v = accs[rt][ct][q] * sc;
                v = v > 0.f ? v : (__expf(v) - 1.f);   // elu
                __builtin_nontemporal_store(v,
                    &out[((size_t)(b * N_ + i0 + il)) * D_ + o0 + ct * 16 + col]);
            }
        }
    }
}

extern "C" void kernel_launch(void* const* d_in, const int* in_sizes, int n_in,
                              void* d_out, int out_size, void* d_ws, size_t ws_size,
                              hipStream_t stream) {
    const float* x   = (const float*)d_in[0];
    const int*   adj = (const int*)d_in[1];
    const float* W   = (const float*)d_in[2];
    const float* a1  = (const float*)d_in[3];
    const float* a2  = (const float*)d_in[4];
    float* out = (float*)d_out;

    char* ws = (char*)d_ws;
    unsigned short* hT = (unsigned short*)ws;                          // 4 MB
    float* s1 = (float*)(ws + (4u << 20));                             // 128 KB
    float* s2 = (float*)(ws + (4u << 20) + (128u << 10));              // 128 KB
    unsigned long long* mask = (unsigned long long*)(ws + (4u << 20) + (512u << 10)); // 1 MB

    void* args[] = {(void*)&x, (void*)&W, (void*)&a1, (void*)&a2, (void*)&adj,
                    (void*)&hT, (void*)&s1, (void*)&s2, (void*)&mask, (void*)&out};
    hipLaunchCooperativeKernel((const void*)k_all, dim3(256), dim3(512), args, 0, stream);
}

// Round 5
// 60.007 us; speedup vs baseline: 1.2423x; 1.2423x over previous
//
#include <hip/hip_runtime.h>
#include <hip/hip_bf16.h>

#define B_ 8
#define N_ 1024
#define D_ 256
#define M_ (B_ * N_)   // 8192

typedef __attribute__((ext_vector_type(8))) short bf16x8;
typedef __attribute__((ext_vector_type(8))) unsigned short u16x8;
typedef __attribute__((ext_vector_type(4))) float f32x4;

__device__ __forceinline__ unsigned short f2bf(float f) {
    unsigned int u = __float_as_uint(f);
    u += 0x7fffu + ((u >> 16) & 1u);   // RNE to bf16
    return (unsigned short)(u >> 16);
}
// HW packed convert: 2 f32 -> 2 bf16 (RNE), 1 instruction
__device__ __forceinline__ unsigned int cvtpk(float lo, float hi) {
    unsigned int r;
    asm("v_cvt_pk_bf16_f32 %0, %1, %2" : "=v"(r) : "v"(lo), "v"(hi));
    return r;
}
__device__ __forceinline__ bf16x8 load8_f32_bf(const float* __restrict__ p) {
    const float4* q = (const float4*)p;
    float4 u = q[0], v = q[1];
    union { unsigned int u4[4]; bf16x8 v8; } c;
    c.u4[0] = cvtpk(u.x, u.y); c.u4[1] = cvtpk(u.z, u.w);
    c.u4[2] = cvtpk(v.x, v.y); c.u4[3] = cvtpk(v.z, v.w);
    return c.v8;
}

// ---- k1: h = x @ W^T -> hT; fused s1/s2; adj->bitmask. 16-row tiles, ------
// grid 512 -> 2 blocks/CU (16 waves/CU) for latency hiding. bid&7 = batch.
__global__ __launch_bounds__(512) void k_hgemm(const float* __restrict__ x,
        const float* __restrict__ W,
        const float* __restrict__ a1, const float* __restrict__ a2,
        const int* __restrict__ adj,
        unsigned short* __restrict__ hT,
        float* __restrict__ s1, float* __restrict__ s2,
        unsigned long long* __restrict__ mask) {
    __shared__ unsigned short xs[16 * 256];        // 8 KB, XOR-swizzled rows
    __shared__ unsigned short tls[8][16][40];      // 10 KB h tile
    __shared__ float spart[8][16][9];              // 4.5 KB s partials
    const int tid = threadIdx.x;
    const int wslot = tid >> 6, lane = tid & 63;
    const int b = blockIdx.x & 7;
    const int m0 = b * N_ + ((blockIdx.x >> 3) << 4);   // 16-row tile base
    const int n0 = wslot * 32;                          // 8 waves = 8 o-tiles
    char* xc = (char*)xs;

    // stage x tile: 16 rows x 256 cols f32 -> bf16, swizzled (32 thr/row)
    {
        const int row = tid >> 5, col8 = (tid & 31) * 8;
        const float4* xp = (const float4*)(x + (m0 + row) * D_ + col8);
        float4 f0 = xp[0], f1 = xp[1];
        union { unsigned int u4[4]; u16x8 v8; } c;
        c.u4[0] = cvtpk(f0.x, f0.y); c.u4[1] = cvtpk(f0.z, f0.w);
        c.u4[2] = cvtpk(f1.x, f1.y); c.u4[3] = cvtpk(f1.z, f1.w);
        const int base = row * 512 + col8 * 2, sw = (row & 7) << 4;
        *(u16x8*)(xc + (base ^ sw)) = c.v8;
    }
    __syncthreads();

    const int r = lane & 15, kg = lane >> 4;
    const int sw = (r & 7) << 4;
    const int abase0 = r * 512;
    const float* wb0 = W + (n0 + r) * D_ + kg * 8;
    const float* wb1 = wb0 + 16 * D_;
    f32x4 z = {0.f, 0.f, 0.f, 0.f};
    f32x4 acc00 = z, acc01 = z;
    bf16x8 nb0 = load8_f32_bf(wb0);
    bf16x8 nb1 = load8_f32_bf(wb1);
    #pragma unroll
    for (int d0 = 0; d0 < D_; d0 += 32) {
        const int kb = (d0 + kg * 8) * 2;
        bf16x8 a0 = *(const bf16x8*)(xc + ((abase0 + kb) ^ sw));
        bf16x8 b0 = nb0, b1 = nb1;
        if (d0 + 32 < D_) {
            nb0 = load8_f32_bf(wb0 + d0 + 32);
            nb1 = load8_f32_bf(wb1 + d0 + 32);
        }
        acc00 = __builtin_amdgcn_mfma_f32_16x16x32_bf16(a0, b0, acc00, 0, 0, 0);
        acc01 = __builtin_amdgcn_mfma_f32_16x16x32_bf16(a0, b1, acc01, 0, 0, 0);
    }
    const int col = lane & 15, rb = (lane >> 4) * 4;
    {
        f32x4 accs2[2] = {acc00, acc01};
        #pragma unroll
        for (int ct = 0; ct < 2; ++ct)
            #pragma unroll
            for (int q = 0; q < 4; ++q)
                tls[wslot][rb + q][ct * 16 + col] = f2bf(accs2[ct][q]);
    }
    __syncthreads();

    // s1/s2 partials via MFMA: A = h rows (tls), B = [a1;a2] 8 rows
    {
        bf16x8 bfr = {0, 0, 0, 0, 0, 0, 0, 0};
        if (r < 8) {
            const float* ap = (r < 4 ? a1 + r * D_ : a2 + (r - 4) * D_) + n0 + kg * 8;
            bfr = load8_f32_bf(ap);
        }
        bf16x8 af0 = *(const bf16x8*)&tls[wslot][r][kg * 8];
        f32x4 s0 = __builtin_amdgcn_mfma_f32_16x16x32_bf16(af0, bfr, z, 0, 0, 0);
        if (col < 8) {
            #pragma unroll
            for (int q = 0; q < 4; ++q) spart[wslot][rb + q][col] = s0[q];
        }
    }

    // transposed, coalesced hT write: hT[b][o][n] (16 n per o-tile now)
    {
        const int bb = m0 >> 10, nbase = m0 & 1023;
        const int ol = lane >> 1, nh = lane & 1;
        unsigned short vv[8];
        #pragma unroll
        for (int q2 = 0; q2 < 8; ++q2) vv[q2] = tls[wslot][nh * 8 + q2][ol];
        u16x8 v8;
        #pragma unroll
        for (int q2 = 0; q2 < 8; ++q2) v8[q2] = vv[q2];
        unsigned short* dst = hT + ((size_t)(bb * D_ + n0 + ol)) * N_ + nbase + nh * 8;
        *(u16x8*)dst = v8;
    }

    __syncthreads();
    // reduce s partials across 8 waves, write s1/s2
    if (tid < 128) {
        const int row = tid >> 3, s = tid & 7;
        float v = 0.f;
        #pragma unroll
        for (int wv = 0; wv < 8; ++wv) v += spart[wv][row][s];
        if (s < 4) s1[s * M_ + m0 + row] = v;
        else       s2[(s - 4) * M_ + m0 + row] = v;
    }

    // adj -> 1-bit mask: 16 rows / 8 waves = 2 rows per wave
    {
        const int wrow = m0 + wslot * 2;
        int a0v[16], a1v[16];
        const int* r0p = adj + (size_t)wrow * N_ + lane;
        const int* r1p = r0p + N_;
        #pragma unroll
        for (int seg = 0; seg < 16; ++seg) {
            a0v[seg] = __builtin_nontemporal_load(r0p + seg * 64);
            a1v[seg] = __builtin_nontemporal_load(r1p + seg * 64);
        }
        unsigned long long w0 = 0, w1 = 0;
        #pragma unroll
        for (int seg = 0; seg < 16; ++seg) {
            unsigned long long b0 = __ballot(a0v[seg] != 0);
            unsigned long long b1 = __ballot(a1v[seg] != 0);
            if (lane == seg) { w0 = b0; w1 = b1; }
        }
        if (lane < 16) {
            mask[(size_t)wrow * 16 + lane]       = w0;
            mask[(size_t)(wrow + 1) * 16 + lane] = w1;
        }
    }
}

// ------- k2: exp-scores -> LDS -> attention GEMM. 16-row tiles, grid 512 ----
// 2 blocks/CU (32 KB Pe), depth-4 B prefetch + depth-1 A prefetch.
__global__ __launch_bounds__(512) void k_fused(
        const unsigned long long* __restrict__ mask,
        const float* __restrict__ s1, const float* __restrict__ s2,
        const unsigned short* __restrict__ hT, float* __restrict__ out) {
    __shared__ unsigned short Pe[16 * 1024];   // 32 KB, XOR-swizzled rows
    __shared__ float invl[16];
    const int b  = blockIdx.x & 7;
    const int i0 = (blockIdx.x >> 3) << 4;
    const int tid = threadIdx.x;

    // phase-2 B pointers; prefetch 4 k-subtiles (independent of phase 1)
    const int w = tid >> 6, lane = tid & 63;
    const int r = lane & 15, kg = lane >> 4;
    const int o0 = w << 5;
    const unsigned short* hTb = hT + (((size_t)b) << 18);
    const unsigned short* pb0 = hTb + (o0 + r) * N_ + kg * 8;
    const unsigned short* pb1 = pb0 + 16 * N_;
    bf16x8 cB0[4], cB1[4];
    #pragma unroll
    for (int j = 0; j < 4; ++j) {
        cB0[j] = *(const bf16x8*)(pb0 + j * 32);
        cB1[j] = *(const bf16x8*)(pb1 + j * 32);
    }

    // ---- phase 1: e = mask_bit * exp(att); 32 thr/row, 32 j's each ---------
    {
        const int ir = tid >> 5, tj = tid & 31;
        const int i = i0 + ir;
        const int gr = b * N_ + i;
        const float s1i0 = s1[0 * M_ + gr], s1i1 = s1[1 * M_ + gr];
        const float s1i2 = s1[2 * M_ + gr], s1i3 = s1[3 * M_ + gr];
        // zone uniform per thread: boundaries 512/768 = tj 16/24
        float base; int ko;
        if (i < 512) {
            if (tj < 16)      { base = 0.f;  ko = -1; }
            else if (tj < 24) { base = s1i2; ko = 2 * M_; }
            else              { base = s1i3; ko = 3 * M_; }
        } else if (i < 768) {
            if (tj < 16)      { base = s1i2; ko = 2 * M_; }
            else if (tj < 24) { base = s1i1; ko = 1 * M_; }
            else              { base = 0.f;  ko = -1; }
        } else {
            if (tj < 16)      { base = s1i3; ko = 3 * M_; }
            else              { base = 0.f;  ko = -1; }
        }
        float dval; { float t = s1i0 + s2[b * N_ + i]; dval = fmaxf(t, 0.2f * t); }
        const unsigned long long m64 = mask[(size_t)gr * 16 + (tj >> 1)];
        const unsigned int m32 = (unsigned int)(m64 >> ((tj & 1) * 32));
        const float* s2k = s2 + b * N_ + (ko < 0 ? 0 : ko) + tj * 32;
        float lsum = 0.f;
        #pragma unroll
        for (int qq = 0; qq < 4; ++qq) {
            const int q8 = (qq + (tj >> 1)) & 3;   // rotated chunk order
            const int j0 = tj * 32 + q8 * 8;
            float sv[8];
            if (ko >= 0) {
                float4 v0 = *(const float4*)(s2k + q8 * 8);
                float4 v1 = *(const float4*)(s2k + q8 * 8 + 4);
                sv[0] = v0.x; sv[1] = v0.y; sv[2] = v0.z; sv[3] = v0.w;
                sv[4] = v1.x; sv[5] = v1.y; sv[6] = v1.z; sv[7] = v1.w;
            } else {
                #pragma unroll
                for (int q = 0; q < 8; ++q) sv[q] = 0.f;
            }
            const unsigned int mb = (m32 >> (q8 * 8)) & 0xffu;
            float evv[8];
            #pragma unroll
            for (int q = 0; q < 8; ++q) {
                const int j = j0 + q;
                float t = base + sv[q];
                float att = fmaxf(t, 0.2f * t);     // leaky relu
                if (j == i) att = dval;             // diag (m0) override
                const float ev = ((mb >> q) & 1u) ? __expf(att) : 0.f;
                lsum += ev;
                evv[q] = ev;
            }
            union { unsigned int u4[4]; u16x8 v8; } c8;
            c8.u4[0] = cvtpk(evv[0], evv[1]); c8.u4[1] = cvtpk(evv[2], evv[3]);
            c8.u4[2] = cvtpk(evv[4], evv[5]); c8.u4[3] = cvtpk(evv[6], evv[7]);
            *(u16x8*)((char*)Pe + ((ir * 2048 + j0 * 2) ^ ((ir & 7) << 4))) = c8.v8;
        }
        lsum += __shfl_xor(lsum, 1, 64);
        lsum += __shfl_xor(lsum, 2, 64);
        lsum += __shfl_xor(lsum, 4, 64);
        lsum += __shfl_xor(lsum, 8, 64);
        lsum += __shfl_xor(lsum, 16, 64);
        if (tj == 0) invl[ir] = 1.f / lsum;
    }
    __syncthreads();

    // ---- phase 2: out = elu((Pe @ h) * invl) ------------------------------
    f32x4 z = {0.f, 0.f, 0.f, 0.f};
    f32x4 acc00 = z, acc01 = z;
    const char* Pc = (const char*)Pe;
    const int sw0 = (r & 7) << 4;
    const int base0 = r * 2048;
    bf16x8 aN = *(const bf16x8*)(Pc + ((base0 + kg * 16) ^ sw0));   // kk=0
    for (int k0 = 0; k0 < N_; k0 += 128) {
        #pragma unroll
        for (int j = 0; j < 4; ++j) {
            const int kk = k0 + j * 32;
            bf16x8 a0 = aN;
            if (kk + 32 < N_)
                aN = *(const bf16x8*)(Pc + ((base0 + (kk + 32 + kg * 8) * 2) ^ sw0));
            bf16x8 b0 = cB0[j], b1 = cB1[j];
            if (kk + 128 < N_) {
                cB0[j] = *(const bf16x8*)(pb0 + kk + 128);
                cB1[j] = *(const bf16x8*)(pb1 + kk + 128);
            }
            acc00 = __builtin_amdgcn_mfma_f32_16x16x32_bf16(a0, b0, acc00, 0, 0, 0);
            acc01 = __builtin_amdgcn_mfma_f32_16x16x32_bf16(a0, b1, acc01, 0, 0, 0);
        }
    }
    const int col = lane & 15, rb = (lane >> 4) << 2;
    {
        f32x4 accs2[2] = {acc00, acc01};
        #pragma unroll
        for (int q = 0; q < 4; ++q) {
            const int il = rb + q;
            const float sc = invl[il];
            #pragma unroll
            for (int ct = 0; ct < 2; ++ct) {
                float v = accs2[ct][q] * sc;
                v = v > 0.f ? v : (__expf(v) - 1.f);   // elu
                __builtin_nontemporal_store(v,
                    &out[((size_t)(b * N_ + i0 + il)) * D_ + o0 + ct * 16 + col]);
            }
        }
    }
}

extern "C" void kernel_launch(void* const* d_in, const int* in_sizes, int n_in,
                              void* d_out, int out_size, void* d_ws, size_t ws_size,
                              hipStream_t stream) {
    const float* x   = (const float*)d_in[0];
    const int*   adj = (const int*)d_in[1];
    const float* W   = (const float*)d_in[2];
    const float* a1  = (const float*)d_in[3];
    const float* a2  = (const float*)d_in[4];
    float* out = (float*)d_out;

    char* ws = (char*)d_ws;
    unsigned short* hT = (unsigned short*)ws;                          // 4 MB
    float* s1 = (float*)(ws + (4u << 20));                             // 128 KB
    float* s2 = (float*)(ws + (4u << 20) + (128u << 10));              // 128 KB
    unsigned long long* mask = (unsigned long long*)(ws + (4u << 20) + (512u << 10)); // 1 MB

    hipLaunchKernelGGL(k_hgemm, dim3(512), dim3(512), 0, stream, x, W, a1, a2, adj, hT, s1, s2, mask);
    hipLaunchKernelGGL(k_fused, dim3(512), dim3(512), 0, stream, mask, s1, s2, hT, out);
}

// Round 7
// 40.388 us; speedup vs baseline: 1.8458x; 1.4858x over previous
//
#include <hip/hip_runtime.h>
#include <hip/hip_bf16.h>

#define B_ 8
#define N_ 1024
#define D_ 256
#define M_ (B_ * N_)   // 8192

typedef __attribute__((ext_vector_type(8))) short bf16x8;
typedef __attribute__((ext_vector_type(8))) unsigned short u16x8;
typedef __attribute__((ext_vector_type(4))) float f32x4;

__device__ __forceinline__ unsigned short f2bf(float f) {
    unsigned int u = __float_as_uint(f);
    u += 0x7fffu + ((u >> 16) & 1u);   // RNE to bf16
    return (unsigned short)(u >> 16);
}
// HW packed convert: 2 f32 -> 2 bf16 (RNE), 1 instruction
__device__ __forceinline__ unsigned int cvtpk(float lo, float hi) {
    unsigned int r;
    asm("v_cvt_pk_bf16_f32 %0, %1, %2" : "=v"(r) : "v"(lo), "v"(hi));
    return r;
}
__device__ __forceinline__ bf16x8 load8_f32_bf(const float* __restrict__ p) {
    const float4* q = (const float4*)p;
    float4 u = q[0], v = q[1];
    union { unsigned int u4[4]; bf16x8 v8; } c;
    c.u4[0] = cvtpk(u.x, u.y); c.u4[1] = cvtpk(u.z, u.w);
    c.u4[2] = cvtpk(v.x, v.y); c.u4[3] = cvtpk(v.z, v.w);
    return c.v8;
}

// ---- k1: h = x @ W^T -> hT; fused s1/s2; adj->bitmask. --------------------
// 32-row tile (same reuse as 39.2µs anchor), 1024 thr = 16 waves = 4 waves/SIMD.
// 16 waves x 16 o-cols each. grid 256, bid&7 = batch (XCD pinning).
__global__ __launch_bounds__(1024, 4) void k_hgemm(const float* __restrict__ x,
        const float* __restrict__ W,
        const float* __restrict__ a1, const float* __restrict__ a2,
        const int* __restrict__ adj,
        unsigned short* __restrict__ hT,
        float* __restrict__ s1, float* __restrict__ s2,
        unsigned long long* __restrict__ mask) {
    __shared__ unsigned short xs[32 * 256];        // 16 KB, XOR-swizzled rows
    __shared__ unsigned short tls[16][32][40];     // 40 KB h tiles (16 waves)
    __shared__ float spart[16][32][9];             // 18 KB s partials
    const int tid = threadIdx.x;
    const int wslot = tid >> 6, lane = tid & 63;
    const int b = blockIdx.x & 7;
    const int m0 = b * N_ + ((blockIdx.x >> 3) << 5);   // 32-row tile base
    const int n0 = wslot * 16;                          // 16 o-cols per wave
    char* xc = (char*)xs;

    // stage x tile: 32 rows x 256 cols f32 -> bf16, swizzled (32 thr/row)
    {
        const int row = tid >> 5, col8 = (tid & 31) * 8;
        const float4* xp = (const float4*)(x + (m0 + row) * D_ + col8);
        float4 f0 = xp[0], f1 = xp[1];
        union { unsigned int u4[4]; u16x8 v8; } c;
        c.u4[0] = cvtpk(f0.x, f0.y); c.u4[1] = cvtpk(f0.z, f0.w);
        c.u4[2] = cvtpk(f1.x, f1.y); c.u4[3] = cvtpk(f1.z, f1.w);
        const int base = row * 512 + col8 * 2, sw = (row & 7) << 4;
        *(u16x8*)(xc + (base ^ sw)) = c.v8;
    }
    __syncthreads();

    const int r = lane & 15, kg = lane >> 4;
    const int sw = (r & 7) << 4;
    const int abase0 = r * 512, abase1 = (16 + r) * 512;
    const float* wb0 = W + (n0 + r) * D_ + kg * 8;     // 16 W rows per wave
    f32x4 z = {0.f, 0.f, 0.f, 0.f};
    f32x4 acc00 = z, acc10 = z;
    bf16x8 nb0 = load8_f32_bf(wb0);
    #pragma unroll
    for (int d0 = 0; d0 < D_; d0 += 32) {
        const int kb = (d0 + kg * 8) * 2;
        bf16x8 a0 = *(const bf16x8*)(xc + ((abase0 + kb) ^ sw));
        bf16x8 a1f = *(const bf16x8*)(xc + ((abase1 + kb) ^ sw));
        bf16x8 b0 = nb0;
        if (d0 + 32 < D_) nb0 = load8_f32_bf(wb0 + d0 + 32);
        acc00 = __builtin_amdgcn_mfma_f32_16x16x32_bf16(a0, b0, acc00, 0, 0, 0);
        acc10 = __builtin_amdgcn_mfma_f32_16x16x32_bf16(a1f, b0, acc10, 0, 0, 0);
    }
    const int col = lane & 15, rb = (lane >> 4) * 4;
    {
        f32x4 accs2[2] = {acc00, acc10};
        #pragma unroll
        for (int rt = 0; rt < 2; ++rt)
            #pragma unroll
            for (int q = 0; q < 4; ++q)
                tls[wslot][rt * 16 + rb + q][col] = f2bf(accs2[rt][q]);
    }
    __syncthreads();

    // s1/s2 partials via MFMA: B = [a1;a2] rows, K-dim = this wave's 16 o-cols.
    // kg>=2 k-slots are other waves' columns: tls there is UNINITIALIZED, so
    // BOTH A and B fragments must be zeroed (0*garbage could be 0*Inf = NaN).
    {
        const bf16x8 zero8 = {0, 0, 0, 0, 0, 0, 0, 0};
        bf16x8 bfr = zero8;
        if (r < 8 && kg < 2) {
            const float* ap = (r < 4 ? a1 + r * D_ : a2 + (r - 4) * D_) + n0 + kg * 8;
            bfr = load8_f32_bf(ap);
        }
        bf16x8 af0 = (kg < 2) ? *(const bf16x8*)&tls[wslot][r][kg * 8]      : zero8;
        bf16x8 af1 = (kg < 2) ? *(const bf16x8*)&tls[wslot][16 + r][kg * 8] : zero8;
        f32x4 s0 = __builtin_amdgcn_mfma_f32_16x16x32_bf16(af0, bfr, z, 0, 0, 0);
        f32x4 s1v = __builtin_amdgcn_mfma_f32_16x16x32_bf16(af1, bfr, z, 0, 0, 0);
        if (col < 8) {
            #pragma unroll
            for (int q = 0; q < 4; ++q) {
                spart[wslot][rb + q][col] = s0[q];
                spart[wslot][16 + rb + q][col] = s1v[q];
            }
        }
    }

    // transposed, coalesced hT write: hT[b][o][n]; wave owns 16 o x 32 n
    {
        const int bb = m0 >> 10, nbase = m0 & 1023;
        const int ol = lane >> 2, nh = lane & 3;
        unsigned short vv[8];
        #pragma unroll
        for (int q2 = 0; q2 < 8; ++q2) vv[q2] = tls[wslot][nh * 8 + q2][ol];
        u16x8 v8;
        #pragma unroll
        for (int q2 = 0; q2 < 8; ++q2) v8[q2] = vv[q2];
        unsigned short* dst = hT + ((size_t)(bb * D_ + n0 + ol)) * N_ + nbase + nh * 8;
        *(u16x8*)dst = v8;
    }

    __syncthreads();
    // reduce s partials across 16 waves, write s1/s2
    if (tid < 256) {
        const int row = tid >> 3, s = tid & 7;
        float v = 0.f;
        #pragma unroll
        for (int wv = 0; wv < 16; ++wv) v += spart[wv][row][s];
        if (s < 4) s1[s * M_ + m0 + row] = v;
        else       s2[(s - 4) * M_ + m0 + row] = v;
    }

    // adj -> 1-bit mask: 32 rows / 16 waves = 2 rows per wave
    {
        const int wrow = m0 + wslot * 2;
        int a0v[16], a1v[16];
        const int* r0p = adj + (size_t)wrow * N_ + lane;
        const int* r1p = r0p + N_;
        #pragma unroll
        for (int seg = 0; seg < 16; ++seg) {
            a0v[seg] = __builtin_nontemporal_load(r0p + seg * 64);
            a1v[seg] = __builtin_nontemporal_load(r1p + seg * 64);
        }
        unsigned long long w0 = 0, w1 = 0;
        #pragma unroll
        for (int seg = 0; seg < 16; ++seg) {
            unsigned long long b0 = __ballot(a0v[seg] != 0);
            unsigned long long b1 = __ballot(a1v[seg] != 0);
            if (lane == seg) { w0 = b0; w1 = b1; }
        }
        if (lane < 16) {
            mask[(size_t)wrow * 16 + lane]       = w0;
            mask[(size_t)(wrow + 1) * 16 + lane] = w1;
        }
    }
}

// ------- k2: exp-scores -> LDS -> attention GEMM. 32-row tile, 1024 thr ----
// 16 waves = 4 waves/SIMD; wave w: 16 o-cols. grid 256, bid&7 = batch.
__global__ __launch_bounds__(1024, 4) void k_fused(
        const unsigned long long* __restrict__ mask,
        const float* __restrict__ s1, const float* __restrict__ s2,
        const unsigned short* __restrict__ hT, float* __restrict__ out) {
    __shared__ unsigned short Pe[32 * 1024];   // 64 KB, XOR-swizzled rows
    __shared__ float invl[32];
    const int b  = blockIdx.x & 7;
    const int i0 = (blockIdx.x >> 3) << 5;
    const int tid = threadIdx.x;

    // phase-2 B pointer (16 hT rows per wave); depth-2 prefetch
    const int w = tid >> 6, lane = tid & 63;
    const int r = lane & 15, kg = lane >> 4;
    const int o0 = w << 4;
    const unsigned short* hTb = hT + (((size_t)b) << 18);
    const unsigned short* pb0 = hTb + (o0 + r) * N_ + kg * 8;
    bf16x8 cA = *(const bf16x8*)pb0;
    bf16x8 cB = *(const bf16x8*)(pb0 + 32);

    // ---- phase 1: e = mask_bit * exp(att); 32 thr/row, 32 j's each ---------
    {
        const int ir = tid >> 5, tj = tid & 31;
        const int i = i0 + ir;
        const int gr = b * N_ + i;
        const float s1i0 = s1[0 * M_ + gr], s1i1 = s1[1 * M_ + gr];
        const float s1i2 = s1[2 * M_ + gr], s1i3 = s1[3 * M_ + gr];
        // zone uniform per thread: boundaries 512/768 = tj 16/24
        float base; int ko;
        if (i < 512) {
            if (tj < 16)      { base = 0.f;  ko = -1; }
            else if (tj < 24) { base = s1i2; ko = 2 * M_; }
            else              { base = s1i3; ko = 3 * M_; }
        } else if (i < 768) {
            if (tj < 16)      { base = s1i2; ko = 2 * M_; }
            else if (tj < 24) { base = s1i1; ko = 1 * M_; }
            else              { base = 0.f;  ko = -1; }
        } else {
            if (tj < 16)      { base = s1i3; ko = 3 * M_; }
            else              { base = 0.f;  ko = -1; }
        }
        float dval; { float t = s1i0 + s2[b * N_ + i]; dval = fmaxf(t, 0.2f * t); }
        const unsigned long long m64 = mask[(size_t)gr * 16 + (tj >> 1)];
        const unsigned int m32 = (unsigned int)(m64 >> ((tj & 1) * 32));
        const float* s2k = s2 + b * N_ + (ko < 0 ? 0 : ko) + tj * 32;
        float lsum = 0.f;
        #pragma unroll
        for (int qq = 0; qq < 4; ++qq) {
            const int q8 = (qq + (tj >> 1)) & 3;   // rotated chunk order
            const int j0 = tj * 32 + q8 * 8;
            float sv[8];
            if (ko >= 0) {
                float4 v0 = *(const float4*)(s2k + q8 * 8);
                float4 v1 = *(const float4*)(s2k + q8 * 8 + 4);
                sv[0] = v0.x; sv[1] = v0.y; sv[2] = v0.z; sv[3] = v0.w;
                sv[4] = v1.x; sv[5] = v1.y; sv[6] = v1.z; sv[7] = v1.w;
            } else {
                #pragma unroll
                for (int q = 0; q < 8; ++q) sv[q] = 0.f;
            }
            const unsigned int mb = (m32 >> (q8 * 8)) & 0xffu;
            float evv[8];
            #pragma unroll
            for (int q = 0; q < 8; ++q) {
                const int j = j0 + q;
                float t = base + sv[q];
                float att = fmaxf(t, 0.2f * t);     // leaky relu
                if (j == i) att = dval;             // diag (m0) override
                const float ev = ((mb >> q) & 1u) ? __expf(att) : 0.f;
                lsum += ev;
                evv[q] = ev;
            }
            union { unsigned int u4[4]; u16x8 v8; } c8;
            c8.u4[0] = cvtpk(evv[0], evv[1]); c8.u4[1] = cvtpk(evv[2], evv[3]);
            c8.u4[2] = cvtpk(evv[4], evv[5]); c8.u4[3] = cvtpk(evv[6], evv[7]);
            *(u16x8*)((char*)Pe + ((ir * 2048 + j0 * 2) ^ ((ir & 7) << 4))) = c8.v8;
        }
        lsum += __shfl_xor(lsum, 1, 64);
        lsum += __shfl_xor(lsum, 2, 64);
        lsum += __shfl_xor(lsum, 4, 64);
        lsum += __shfl_xor(lsum, 8, 64);
        lsum += __shfl_xor(lsum, 16, 64);
        if (tj == 0) invl[ir] = 1.f / lsum;
    }
    __syncthreads();

    // ---- phase 2: out = elu((Pe @ h) * invl), depth-2 B prefetch ----------
    f32x4 z = {0.f, 0.f, 0.f, 0.f};
    f32x4 acc00 = z, acc10 = z;
    const char* Pc = (const char*)Pe;
    const int sw0 = (r & 7) << 4;
    const int base0 = r * 2048, base1 = (16 + r) * 2048;
    #pragma unroll 2
    for (int k0 = 0; k0 < N_; k0 += 64) {
        int kb = (k0 + kg * 8) * 2;
        bf16x8 a0 = *(const bf16x8*)(Pc + ((base0 + kb) ^ sw0));
        bf16x8 a1f = *(const bf16x8*)(Pc + ((base1 + kb) ^ sw0));
        bf16x8 b0 = cA;
        if (k0 + 64 < N_) cA = *(const bf16x8*)(pb0 + k0 + 64);
        acc00 = __builtin_amdgcn_mfma_f32_16x16x32_bf16(a0, b0, acc00, 0, 0, 0);
        acc10 = __builtin_amdgcn_mfma_f32_16x16x32_bf16(a1f, b0, acc10, 0, 0, 0);
        kb = (k0 + 32 + kg * 8) * 2;
        a0 = *(const bf16x8*)(Pc + ((base0 + kb) ^ sw0));
        a1f = *(const bf16x8*)(Pc + ((base1 + kb) ^ sw0));
        bf16x8 b1 = cB;
        if (k0 + 96 < N_) cB = *(const bf16x8*)(pb0 + k0 + 96);
        acc00 = __builtin_amdgcn_mfma_f32_16x16x32_bf16(a0, b1, acc00, 0, 0, 0);
        acc10 = __builtin_amdgcn_mfma_f32_16x16x32_bf16(a1f, b1, acc10, 0, 0, 0);
    }
    const int col = lane & 15, rb = (lane >> 4) << 2;
    {
        f32x4 accs2[2] = {acc00, acc10};
        #pragma unroll
        for (int rt = 0; rt < 2; ++rt) {
            #pragma unroll
            for (int q = 0; q < 4; ++q) {
                const int il = rt * 16 + rb + q;
                const float sc = invl[il];
                float v = accs2[rt][q] * sc;
                v = v > 0.f ? v : (__expf(v) - 1.f);   // elu
                __builtin_nontemporal_store(v,
                    &out[((size_t)(b * N_ + i0 + il)) * D_ + o0 + col]);
            }
        }
    }
}

extern "C" void kernel_launch(void* const* d_in, const int* in_sizes, int n_in,
                              void* d_out, int out_size, void* d_ws, size_t ws_size,
                              hipStream_t stream) {
    const float* x   = (const float*)d_in[0];
    const int*   adj = (const int*)d_in[1];
    const float* W   = (const float*)d_in[2];
    const float* a1  = (const float*)d_in[3];
    const float* a2  = (const float*)d_in[4];
    float* out = (float*)d_out;

    char* ws = (char*)d_ws;
    unsigned short* hT = (unsigned short*)ws;                          // 4 MB
    float* s1 = (float*)(ws + (4u << 20));                             // 128 KB
    float* s2 = (float*)(ws + (4u << 20) + (128u << 10));              // 128 KB
    unsigned long long* mask = (unsigned long long*)(ws + (4u << 20) + (512u << 10)); // 1 MB

    hipLaunchKernelGGL(k_hgemm, dim3(256), dim3(1024), 0, stream, x, W, a1, a2, adj, hT, s1, s2, mask);
    hipLaunchKernelGGL(k_fused, dim3(256), dim3(1024), 0, stream, mask, s1, s2, hT, out);
}